// Round 1
// baseline (383.325 us; speedup 1.0000x reference)
//
#include <hip/hip_runtime.h>

#define DIM     1024
#define BATCH   512
#define OUTD    5377
#define NHEADS  10
#define NLAYERS 5

// ---------------- grouping: bucket batches by rule_len ----------------
__global__ void group_kernel(const int* __restrict__ rule_len,
                             int* __restrict__ bidx,
                             int* __restrict__ gstart,
                             int* __restrict__ gcount) {
    __shared__ int s_count[NHEADS];
    __shared__ int s_fill[NHEADS];
    int t = threadIdx.x;
    if (t < NHEADS) s_count[t] = 0;
    __syncthreads();
    int h = rule_len[t];
    atomicAdd(&s_count[h], 1);
    __syncthreads();
    if (t == 0) {
        int acc = 0;
        for (int i = 0; i < NHEADS; ++i) {
            gstart[i] = acc;
            gcount[i] = s_count[i];
            s_fill[i] = acc;
            acc += s_count[i];
        }
    }
    __syncthreads();
    int pos = atomicAdd(&s_fill[h], 1);
    bidx[pos] = t;
}

// ---------------- MLP GEMM: C[m,n] = sum_k A[m,k]*W[n,k] + bias[n] ----------------
#define MBM 32
#define MBN 64
#define MBK 32

__global__ __launch_bounds__(256) void mlp_gemm(
    const float* __restrict__ A,     // M x K row-major
    const float* __restrict__ W,     // N x K row-major
    const float* __restrict__ bias,  // N
    float* __restrict__ C,           // M x N
    int M, int N, int K)
{
    __shared__ float As[MBK][MBM + 4];
    __shared__ float Ws[MBK][MBN + 4];

    int tid = threadIdx.x;
    int n0 = blockIdx.x * MBN;
    int m0 = blockIdx.y * MBM;
    int tx = tid & 15;      // 16 -> 64 cols (x4)
    int ty = tid >> 4;      // 16 -> 32 rows (x2)

    float acc[2][4] = {};

    int arow = tid >> 3;          // 0..31
    int acol = (tid & 7) * 4;     // 0..28
    int wrow = tid >> 2;          // 0..63
    int wcol = (tid & 3) * 8;     // 0..24

    for (int k0 = 0; k0 < K; k0 += MBK) {
        {
            float4 v = *(const float4*)(A + (size_t)(m0 + arow) * K + k0 + acol);
            As[acol + 0][arow] = v.x;
            As[acol + 1][arow] = v.y;
            As[acol + 2][arow] = v.z;
            As[acol + 3][arow] = v.w;

            const float* wp = W + (size_t)(n0 + wrow) * K + k0 + wcol;
            float4 w0 = *(const float4*)(wp);
            float4 w1 = *(const float4*)(wp + 4);
            Ws[wcol + 0][wrow] = w0.x;
            Ws[wcol + 1][wrow] = w0.y;
            Ws[wcol + 2][wrow] = w0.z;
            Ws[wcol + 3][wrow] = w0.w;
            Ws[wcol + 4][wrow] = w1.x;
            Ws[wcol + 5][wrow] = w1.y;
            Ws[wcol + 6][wrow] = w1.z;
            Ws[wcol + 7][wrow] = w1.w;
        }
        __syncthreads();
        #pragma unroll
        for (int kk = 0; kk < MBK; ++kk) {
            float a0 = As[kk][ty * 2 + 0];
            float a1 = As[kk][ty * 2 + 1];
            float4 wv = *(const float4*)&Ws[kk][tx * 4];
            acc[0][0] += a0 * wv.x; acc[0][1] += a0 * wv.y;
            acc[0][2] += a0 * wv.z; acc[0][3] += a0 * wv.w;
            acc[1][0] += a1 * wv.x; acc[1][1] += a1 * wv.y;
            acc[1][2] += a1 * wv.z; acc[1][3] += a1 * wv.w;
        }
        __syncthreads();
    }

    float4 b4 = *(const float4*)(bias + n0 + tx * 4);
    #pragma unroll
    for (int i = 0; i < 2; ++i) {
        int m = m0 + ty * 2 + i;
        float4 o;
        o.x = acc[i][0] + b4.x;
        o.y = acc[i][1] + b4.y;
        o.z = acc[i][2] + b4.z;
        o.w = acc[i][3] + b4.w;
        *(float4*)(C + (size_t)m * N + n0 + tx * 4) = o;
    }
}

// ---------------- grouped head GEMM ----------------
#define HBM 64
#define HBN 64
#define HBK 32

__global__ __launch_bounds__(256) void head_gemm(
    const float* __restrict__ H,       // BATCH x DIM
    const float* __restrict__ Wh,      // NHEADS x OUTD x DIM
    const float* __restrict__ bh,      // NHEADS x OUTD
    const int* __restrict__ bidx,
    const int* __restrict__ gstart,
    const int* __restrict__ gcount,
    float* __restrict__ out)           // BATCH x OUTD
{
    int head = blockIdx.z;
    int cnt = gcount[head];
    int m0 = blockIdx.y * HBM;
    if (m0 >= cnt) return;
    int n0 = blockIdx.x * HBN;
    int start = gstart[head];

    __shared__ float As[HBK][HBM + 4];
    __shared__ float Ws[HBK][HBN + 4];
    __shared__ int s_b[HBM];

    int tid = threadIdx.x;
    if (tid < HBM) {
        int mi = m0 + tid;
        s_b[tid] = (mi < cnt) ? bidx[start + mi] : -1;
    }
    __syncthreads();

    const float* WhL = Wh + (size_t)head * OUTD * DIM;
    int tx = tid & 15, ty = tid >> 4;
    float acc[4][4] = {};

    int lrow = tid >> 2;          // 0..63 (shared by A and W loads)
    int lcol = (tid & 3) * 8;     // 0..24
    int b_r = s_b[lrow];
    int wn = n0 + lrow;
    const float* hp  = (b_r >= 0)  ? (H + (size_t)b_r * DIM) : nullptr;
    const float* wp0 = (wn < OUTD) ? (WhL + (size_t)wn * DIM) : nullptr;

    for (int k0 = 0; k0 < DIM; k0 += HBK) {
        float4 a0 = {}, a1 = {};
        if (hp) {
            a0 = *(const float4*)(hp + k0 + lcol);
            a1 = *(const float4*)(hp + k0 + lcol + 4);
        }
        As[lcol + 0][lrow] = a0.x;
        As[lcol + 1][lrow] = a0.y;
        As[lcol + 2][lrow] = a0.z;
        As[lcol + 3][lrow] = a0.w;
        As[lcol + 4][lrow] = a1.x;
        As[lcol + 5][lrow] = a1.y;
        As[lcol + 6][lrow] = a1.z;
        As[lcol + 7][lrow] = a1.w;

        float4 w0 = {}, w1 = {};
        if (wp0) {
            w0 = *(const float4*)(wp0 + k0 + lcol);
            w1 = *(const float4*)(wp0 + k0 + lcol + 4);
        }
        Ws[lcol + 0][lrow] = w0.x;
        Ws[lcol + 1][lrow] = w0.y;
        Ws[lcol + 2][lrow] = w0.z;
        Ws[lcol + 3][lrow] = w0.w;
        Ws[lcol + 4][lrow] = w1.x;
        Ws[lcol + 5][lrow] = w1.y;
        Ws[lcol + 6][lrow] = w1.z;
        Ws[lcol + 7][lrow] = w1.w;

        __syncthreads();
        #pragma unroll
        for (int kk = 0; kk < HBK; ++kk) {
            float4 av = *(const float4*)&As[kk][ty * 4];
            float4 wv = *(const float4*)&Ws[kk][tx * 4];
            acc[0][0] += av.x * wv.x; acc[0][1] += av.x * wv.y;
            acc[0][2] += av.x * wv.z; acc[0][3] += av.x * wv.w;
            acc[1][0] += av.y * wv.x; acc[1][1] += av.y * wv.y;
            acc[1][2] += av.y * wv.z; acc[1][3] += av.y * wv.w;
            acc[2][0] += av.z * wv.x; acc[2][1] += av.z * wv.y;
            acc[2][2] += av.z * wv.z; acc[2][3] += av.z * wv.w;
            acc[3][0] += av.w * wv.x; acc[3][1] += av.w * wv.y;
            acc[3][2] += av.w * wv.z; acc[3][3] += av.w * wv.w;
        }
        __syncthreads();
    }

    #pragma unroll
    for (int i = 0; i < 4; ++i) {
        int b = s_b[ty * 4 + i];
        if (b < 0) continue;
        #pragma unroll
        for (int j = 0; j < 4; ++j) {
            int n = n0 + tx * 4 + j;
            if (n < OUTD) {
                out[(size_t)b * OUTD + n] = acc[i][j] + bh[(size_t)head * OUTD + n];
            }
        }
    }
}

extern "C" void kernel_launch(void* const* d_in, const int* in_sizes, int n_in,
                              void* d_out, int out_size, void* d_ws, size_t ws_size,
                              hipStream_t stream) {
    const float* latent  = (const float*)d_in[0];
    const float* W_mlp   = (const float*)d_in[1];
    const float* b_mlp   = (const float*)d_in[2];
    const float* W_heads = (const float*)d_in[3];
    const float* b_heads = (const float*)d_in[4];
    const int*   rule_len = (const int*)d_in[5];
    float* out = (float*)d_out;

    float* h0 = (float*)d_ws;
    float* h1 = h0 + (size_t)BATCH * DIM;
    int* bidx   = (int*)(h1 + (size_t)BATCH * DIM);
    int* gstart = bidx + BATCH;
    int* gcount = gstart + 16;

    group_kernel<<<1, BATCH, 0, stream>>>(rule_len, bidx, gstart, gcount);

    dim3 mgrid(DIM / MBN, BATCH / MBM);
    const float* src = latent;
    float* dst = h0;
    for (int l = 0; l < NLAYERS; ++l) {
        mlp_gemm<<<mgrid, 256, 0, stream>>>(src,
                                            W_mlp + (size_t)l * DIM * DIM,
                                            b_mlp + (size_t)l * DIM,
                                            dst, BATCH, DIM, DIM);
        src = dst;
        dst = (dst == h0) ? h1 : h0;
    }

    dim3 hgrid((OUTD + HBN - 1) / HBN, BATCH / HBM, NHEADS);
    head_gemm<<<hgrid, 256, 0, stream>>>(src, W_heads, b_heads,
                                         bidx, gstart, gcount, out);
}

// Round 2
// 139.059 us; speedup vs baseline: 2.7566x; 2.7566x over previous
//
#include <hip/hip_runtime.h>

#define DIM     1024
#define BATCH   512
#define OUTD    5377
#define NHEADS  10
#define NLAYERS 5

typedef __attribute__((ext_vector_type(4))) float f32x4;
typedef __attribute__((ext_vector_type(8))) short bf16x8;

__device__ __forceinline__ unsigned short f2bf(float f) {
    unsigned u = __builtin_bit_cast(unsigned, f);
    u = (u + 0x7FFFu + ((u >> 16) & 1u)) >> 16;
    return (unsigned short)u;
}
__device__ __forceinline__ float bf2f(unsigned short h) {
    unsigned u = ((unsigned)h) << 16;
    return __builtin_bit_cast(float, u);
}

// ---------------- grouping: bucket batches by rule_len ----------------
__global__ void group_kernel(const int* __restrict__ rule_len,
                             int* __restrict__ bidx,
                             int* __restrict__ gstart,
                             int* __restrict__ gcount) {
    __shared__ int s_count[NHEADS];
    __shared__ int s_fill[NHEADS];
    int t = threadIdx.x;
    if (t < NHEADS) s_count[t] = 0;
    __syncthreads();
    int h = rule_len[t];
    atomicAdd(&s_count[h], 1);
    __syncthreads();
    if (t == 0) {
        int acc = 0;
        for (int i = 0; i < NHEADS; ++i) {
            gstart[i] = acc;
            gcount[i] = s_count[i];
            s_fill[i] = acc;
            acc += s_count[i];
        }
    }
    __syncthreads();
    int pos = atomicAdd(&s_fill[h], 1);
    bidx[pos] = t;
}

// ---------------- latent f32 -> bf16 ----------------
__global__ void convert_latent(const float* __restrict__ in,
                               unsigned short* __restrict__ out) {
    int i = blockIdx.x * blockDim.x + threadIdx.x;   // one float4 per thread
    float4 v = ((const float4*)in)[i];
    ushort4 o;
    o.x = f2bf(v.x); o.y = f2bf(v.y); o.z = f2bf(v.z); o.w = f2bf(v.w);
    ((ushort4*)out)[i] = o;
}

// ---------------- MLP layer: C = A @ W^T + bias  (MFMA, W split hi/lo) -------
// A: BATCH x DIM bf16, W: DIM x DIM f32 (row n holds weights for output n)
#define LDK 72   // padded bf16 leading dim (144 B = 36 banks -> 2-way, free)

__global__ __launch_bounds__(256) void mlp_mfma(
    const unsigned short* __restrict__ A,
    const float* __restrict__ W,
    const float* __restrict__ bias,
    unsigned short* __restrict__ C)
{
    __shared__ __align__(16) unsigned short As[32][LDK];
    __shared__ __align__(16) unsigned short Whi[32][LDK];
    __shared__ __align__(16) unsigned short Wlo[32][LDK];

    const int tid = threadIdx.x;
    const int n0 = blockIdx.x * 32;
    const int m0 = blockIdx.y * 32;
    const int lane = tid & 63;
    const int wid = tid >> 6;
    const int wm = (wid >> 1) * 16;
    const int wn = (wid & 1) * 16;

    f32x4 acc = {0.f, 0.f, 0.f, 0.f};

    const int ar = tid >> 3;          // 0..31
    const int ac = (tid & 7) * 8;     // 0..56 (bf16 units)
    const int wr = tid >> 4;          // 0..15
    const int wc = (tid & 15) * 4;    // 0..60 (f32 units)

    const unsigned short* Ap = A + (size_t)(m0 + ar) * DIM + ac;
    const float* Wp0 = W + (size_t)(n0 + wr) * DIM + wc;
    const float* Wp1 = W + (size_t)(n0 + wr + 16) * DIM + wc;

    for (int k0 = 0; k0 < DIM; k0 += 64) {
        *(uint4*)&As[ar][ac] = *(const uint4*)(Ap + k0);
        {
            float4 w = *(const float4*)(Wp0 + k0);
            ushort4 hi, lo;
            hi.x = f2bf(w.x); lo.x = f2bf(w.x - bf2f(hi.x));
            hi.y = f2bf(w.y); lo.y = f2bf(w.y - bf2f(hi.y));
            hi.z = f2bf(w.z); lo.z = f2bf(w.z - bf2f(hi.z));
            hi.w = f2bf(w.w); lo.w = f2bf(w.w - bf2f(hi.w));
            *(ushort4*)&Whi[wr][wc] = hi;
            *(ushort4*)&Wlo[wr][wc] = lo;
        }
        {
            float4 w = *(const float4*)(Wp1 + k0);
            ushort4 hi, lo;
            hi.x = f2bf(w.x); lo.x = f2bf(w.x - bf2f(hi.x));
            hi.y = f2bf(w.y); lo.y = f2bf(w.y - bf2f(hi.y));
            hi.z = f2bf(w.z); lo.z = f2bf(w.z - bf2f(hi.z));
            hi.w = f2bf(w.w); lo.w = f2bf(w.w - bf2f(hi.w));
            *(ushort4*)&Whi[wr + 16][wc] = hi;
            *(ushort4*)&Wlo[wr + 16][wc] = lo;
        }
        __syncthreads();
        #pragma unroll
        for (int kk = 0; kk < 2; ++kk) {
            const int ko = kk * 32 + (lane >> 4) * 8;
            bf16x8 a  = *(const bf16x8*)&As[wm + (lane & 15)][ko];
            bf16x8 bh = *(const bf16x8*)&Whi[wn + (lane & 15)][ko];
            bf16x8 bl = *(const bf16x8*)&Wlo[wn + (lane & 15)][ko];
            acc = __builtin_amdgcn_mfma_f32_16x16x32_bf16(a, bh, acc, 0, 0, 0);
            acc = __builtin_amdgcn_mfma_f32_16x16x32_bf16(a, bl, acc, 0, 0, 0);
        }
        __syncthreads();
    }

    const int cn = n0 + wn + (lane & 15);
    const float bn = bias[cn];
    const int rbase = m0 + wm + (lane >> 4) * 4;
    #pragma unroll
    for (int j = 0; j < 4; ++j) {
        C[(size_t)(rbase + j) * DIM + cn] = f2bf(acc[j] + bn);
    }
}

// ---------------- grouped head GEMM (MFMA, W split hi/lo, inline cvt) --------
__global__ __launch_bounds__(256) void head_mfma(
    const unsigned short* __restrict__ H,   // BATCH x DIM bf16
    const float* __restrict__ Wh,           // NHEADS x OUTD x DIM f32
    const float* __restrict__ bh,           // NHEADS x OUTD f32
    const int* __restrict__ bidx,
    const int* __restrict__ gstart,
    const int* __restrict__ gcount,
    float* __restrict__ out)                // BATCH x OUTD f32
{
    const int head = blockIdx.z;
    const int cnt = gcount[head];
    const int m0 = blockIdx.y * 64;
    if (m0 >= cnt) return;
    const int n0 = blockIdx.x * 64;

    __shared__ __align__(16) unsigned short As[64][LDK];
    __shared__ __align__(16) unsigned short Whi[64][LDK];
    __shared__ __align__(16) unsigned short Wlo[64][LDK];
    __shared__ int s_b[64];

    const int tid = threadIdx.x;
    if (tid < 64) {
        int mi = m0 + tid;
        s_b[tid] = (mi < cnt) ? bidx[gstart[head] + mi] : -1;
    }
    __syncthreads();

    const int lane = tid & 63;
    const int wid = tid >> 6;
    const int wm = (wid >> 1) * 32;
    const int wn = (wid & 1) * 32;

    f32x4 acc[2][2] = {};

    // A staging: 2 passes of 32 rows
    const int ar = tid >> 3;          // 0..31
    const int ac = (tid & 7) * 8;
    int b0 = s_b[ar];       if (b0 < 0) b0 = 0;
    int b1 = s_b[ar + 32];  if (b1 < 0) b1 = 0;
    const unsigned short* Ap0 = H + (size_t)b0 * DIM + ac;
    const unsigned short* Ap1 = H + (size_t)b1 * DIM + ac;

    // W staging: 4 passes of 16 rows, row index clamped at edge
    const int wr = tid >> 4;          // 0..15
    const int wc = (tid & 15) * 4;
    const float* WhL = Wh + (size_t)head * OUTD * DIM;
    const float* Wp[4];
    #pragma unroll
    for (int p = 0; p < 4; ++p) {
        int r = n0 + wr + p * 16;
        if (r > OUTD - 1) r = OUTD - 1;
        Wp[p] = WhL + (size_t)r * DIM + wc;
    }

    for (int k0 = 0; k0 < DIM; k0 += 64) {
        *(uint4*)&As[ar][ac]      = *(const uint4*)(Ap0 + k0);
        *(uint4*)&As[ar + 32][ac] = *(const uint4*)(Ap1 + k0);
        #pragma unroll
        for (int p = 0; p < 4; ++p) {
            float4 w = *(const float4*)(Wp[p] + k0);
            ushort4 hi, lo;
            hi.x = f2bf(w.x); lo.x = f2bf(w.x - bf2f(hi.x));
            hi.y = f2bf(w.y); lo.y = f2bf(w.y - bf2f(hi.y));
            hi.z = f2bf(w.z); lo.z = f2bf(w.z - bf2f(hi.z));
            hi.w = f2bf(w.w); lo.w = f2bf(w.w - bf2f(hi.w));
            *(ushort4*)&Whi[wr + p * 16][wc] = hi;
            *(ushort4*)&Wlo[wr + p * 16][wc] = lo;
        }
        __syncthreads();
        #pragma unroll
        for (int kk = 0; kk < 2; ++kk) {
            const int ko = kk * 32 + (lane >> 4) * 8;
            bf16x8 a0 = *(const bf16x8*)&As[wm + (lane & 15)][ko];
            bf16x8 a1 = *(const bf16x8*)&As[wm + 16 + (lane & 15)][ko];
            bf16x8 h0 = *(const bf16x8*)&Whi[wn + (lane & 15)][ko];
            bf16x8 h1 = *(const bf16x8*)&Whi[wn + 16 + (lane & 15)][ko];
            bf16x8 l0 = *(const bf16x8*)&Wlo[wn + (lane & 15)][ko];
            bf16x8 l1 = *(const bf16x8*)&Wlo[wn + 16 + (lane & 15)][ko];
            acc[0][0] = __builtin_amdgcn_mfma_f32_16x16x32_bf16(a0, h0, acc[0][0], 0, 0, 0);
            acc[0][0] = __builtin_amdgcn_mfma_f32_16x16x32_bf16(a0, l0, acc[0][0], 0, 0, 0);
            acc[0][1] = __builtin_amdgcn_mfma_f32_16x16x32_bf16(a0, h1, acc[0][1], 0, 0, 0);
            acc[0][1] = __builtin_amdgcn_mfma_f32_16x16x32_bf16(a0, l1, acc[0][1], 0, 0, 0);
            acc[1][0] = __builtin_amdgcn_mfma_f32_16x16x32_bf16(a1, h0, acc[1][0], 0, 0, 0);
            acc[1][0] = __builtin_amdgcn_mfma_f32_16x16x32_bf16(a1, l0, acc[1][0], 0, 0, 0);
            acc[1][1] = __builtin_amdgcn_mfma_f32_16x16x32_bf16(a1, h1, acc[1][1], 0, 0, 0);
            acc[1][1] = __builtin_amdgcn_mfma_f32_16x16x32_bf16(a1, l1, acc[1][1], 0, 0, 0);
        }
        __syncthreads();
    }

    const float* bhL = bh + (size_t)head * OUTD;
    #pragma unroll
    for (int fm = 0; fm < 2; ++fm) {
        #pragma unroll
        for (int fn = 0; fn < 2; ++fn) {
            int n = n0 + wn + fn * 16 + (lane & 15);
            if (n >= OUTD) continue;
            float bn = bhL[n];
            #pragma unroll
            for (int j = 0; j < 4; ++j) {
                int mi = wm + fm * 16 + (lane >> 4) * 4 + j;
                int b = s_b[mi];
                if (b >= 0) out[(size_t)b * OUTD + n] = acc[fm][fn][j] + bn;
            }
        }
    }
}

extern "C" void kernel_launch(void* const* d_in, const int* in_sizes, int n_in,
                              void* d_out, int out_size, void* d_ws, size_t ws_size,
                              hipStream_t stream) {
    const float* latent   = (const float*)d_in[0];
    const float* W_mlp    = (const float*)d_in[1];
    const float* b_mlp    = (const float*)d_in[2];
    const float* W_heads  = (const float*)d_in[3];
    const float* b_heads  = (const float*)d_in[4];
    const int*   rule_len = (const int*)d_in[5];
    float* out = (float*)d_out;

    unsigned short* h0 = (unsigned short*)d_ws;
    unsigned short* h1 = h0 + (size_t)BATCH * DIM;
    int* bidx   = (int*)(h1 + (size_t)BATCH * DIM);
    int* gstart = bidx + BATCH;
    int* gcount = gstart + 16;

    group_kernel<<<1, BATCH, 0, stream>>>(rule_len, bidx, gstart, gcount);

    // latent -> bf16 in h0
    convert_latent<<<(BATCH * DIM / 4) / 256, 256, 0, stream>>>(latent, h0);

    dim3 mgrid(DIM / 32, BATCH / 32);
    const unsigned short* src = h0;
    unsigned short* dst = h1;
    for (int l = 0; l < NLAYERS; ++l) {
        mlp_mfma<<<mgrid, 256, 0, stream>>>(src,
                                            W_mlp + (size_t)l * DIM * DIM,
                                            b_mlp + (size_t)l * DIM,
                                            dst);
        const unsigned short* t = dst;
        dst = (unsigned short*)(src == h0 ? h0 : h1);
        dst = (dst == h0) ? h1 : h0;           // ping-pong
        dst = (unsigned short*)((t == h0) ? h1 : h0);
        src = t;
    }

    dim3 hgrid((OUTD + 63) / 64, BATCH / 64, NHEADS);
    head_mfma<<<hgrid, 256, 0, stream>>>(src, W_heads, b_heads,
                                         bidx, gstart, gcount, out);
}

// Round 3
// 123.049 us; speedup vs baseline: 3.1152x; 1.1301x over previous
//
#include <hip/hip_runtime.h>

#define DIM     1024
#define BATCH   512
#define OUTD    5377
#define NHEADS  10
#define NLAYERS 5
#define LDK     72   // padded bf16 leading dim (144 B -> benign 2-way bank aliasing)

typedef __attribute__((ext_vector_type(4))) float f32x4;
typedef __attribute__((ext_vector_type(8))) short bf16x8;

__device__ __forceinline__ unsigned short f2bf(float f) {
    unsigned u = __builtin_bit_cast(unsigned, f);
    u = (u + 0x7FFFu + ((u >> 16) & 1u)) >> 16;
    return (unsigned short)u;
}
__device__ __forceinline__ float bf2f(unsigned short h) {
    unsigned u = ((unsigned)h) << 16;
    return __builtin_bit_cast(float, u);
}

// ---------------- grouping: bucket batches by rule_len ----------------
__global__ void group_kernel(const int* __restrict__ rule_len,
                             int* __restrict__ bidx,
                             int* __restrict__ gstart,
                             int* __restrict__ gcount) {
    __shared__ int s_count[NHEADS];
    __shared__ int s_fill[NHEADS];
    int t = threadIdx.x;
    if (t < NHEADS) s_count[t] = 0;
    __syncthreads();
    int h = rule_len[t];
    atomicAdd(&s_count[h], 1);
    __syncthreads();
    if (t == 0) {
        int acc = 0;
        for (int i = 0; i < NHEADS; ++i) {
            gstart[i] = acc;
            gcount[i] = s_count[i];
            s_fill[i] = acc;
            acc += s_count[i];
        }
    }
    __syncthreads();
    int pos = atomicAdd(&s_fill[h], 1);
    bidx[pos] = t;
}

// ---------------- latent f32 -> bf16 ----------------
__global__ void convert_latent(const float* __restrict__ in,
                               unsigned short* __restrict__ out) {
    int i = blockIdx.x * blockDim.x + threadIdx.x;   // one float4 per thread
    float4 v = ((const float4*)in)[i];
    ushort4 o;
    o.x = f2bf(v.x); o.y = f2bf(v.y); o.z = f2bf(v.z); o.w = f2bf(v.w);
    ((ushort4*)out)[i] = o;
}

// ---------------- MLP layer: C = A @ W^T + bias  (MFMA, W hi/lo, pipelined) --
__global__ __launch_bounds__(256) void mlp_mfma(
    const unsigned short* __restrict__ A,
    const float* __restrict__ W,
    const float* __restrict__ bias,
    unsigned short* __restrict__ C)
{
    __shared__ __align__(16) unsigned short As[2][32][LDK];
    __shared__ __align__(16) unsigned short Whi[2][32][LDK];
    __shared__ __align__(16) unsigned short Wlo[2][32][LDK];

    const int tid = threadIdx.x;
    const int n0 = blockIdx.x * 32;
    const int m0 = blockIdx.y * 32;
    const int lane = tid & 63;
    const int wid = tid >> 6;
    const int wm = (wid >> 1) * 16;
    const int wn = (wid & 1) * 16;

    f32x4 acc = {0.f, 0.f, 0.f, 0.f};

    const int ar = tid >> 3;          // 0..31
    const int ac = (tid & 7) * 8;     // 0..56 bf16 units
    const int wr = tid >> 4;          // 0..15
    const int wc = (tid & 15) * 4;    // 0..60 f32 units

    const unsigned short* Ap = A + (size_t)(m0 + ar) * DIM + ac;
    const float* Wp0 = W + (size_t)(n0 + wr) * DIM + wc;
    const float* Wp1 = W + (size_t)(n0 + wr + 16) * DIM + wc;

    uint4  ra  = *(const uint4*)(Ap);
    float4 rw0 = *(const float4*)(Wp0);
    float4 rw1 = *(const float4*)(Wp1);

    for (int t = 0; t < DIM / 64; ++t) {
        const int cur = t & 1;
        *(uint4*)&As[cur][ar][ac] = ra;
        {
            ushort4 hi, lo;
            hi.x = f2bf(rw0.x); lo.x = f2bf(rw0.x - bf2f(hi.x));
            hi.y = f2bf(rw0.y); lo.y = f2bf(rw0.y - bf2f(hi.y));
            hi.z = f2bf(rw0.z); lo.z = f2bf(rw0.z - bf2f(hi.z));
            hi.w = f2bf(rw0.w); lo.w = f2bf(rw0.w - bf2f(hi.w));
            *(ushort4*)&Whi[cur][wr][wc] = hi;
            *(ushort4*)&Wlo[cur][wr][wc] = lo;
            hi.x = f2bf(rw1.x); lo.x = f2bf(rw1.x - bf2f(hi.x));
            hi.y = f2bf(rw1.y); lo.y = f2bf(rw1.y - bf2f(hi.y));
            hi.z = f2bf(rw1.z); lo.z = f2bf(rw1.z - bf2f(hi.z));
            hi.w = f2bf(rw1.w); lo.w = f2bf(rw1.w - bf2f(hi.w));
            *(ushort4*)&Whi[cur][wr + 16][wc] = hi;
            *(ushort4*)&Wlo[cur][wr + 16][wc] = lo;
        }
        __syncthreads();
        if (t < DIM / 64 - 1) {
            const int k0 = (t + 1) * 64;
            ra  = *(const uint4*)(Ap + k0);
            rw0 = *(const float4*)(Wp0 + k0);
            rw1 = *(const float4*)(Wp1 + k0);
        }
        #pragma unroll
        for (int kk = 0; kk < 2; ++kk) {
            const int ko = kk * 32 + (lane >> 4) * 8;
            bf16x8 a  = *(const bf16x8*)&As[cur][wm + (lane & 15)][ko];
            bf16x8 bh = *(const bf16x8*)&Whi[cur][wn + (lane & 15)][ko];
            bf16x8 bl = *(const bf16x8*)&Wlo[cur][wn + (lane & 15)][ko];
            acc = __builtin_amdgcn_mfma_f32_16x16x32_bf16(a, bh, acc, 0, 0, 0);
            acc = __builtin_amdgcn_mfma_f32_16x16x32_bf16(a, bl, acc, 0, 0, 0);
        }
        // single barrier per step: write(t+2) to this buffer is fenced by
        // the barrier inside step t+1.
    }

    const int cn = n0 + wn + (lane & 15);
    const float bn = bias[cn];
    const int rbase = m0 + wm + (lane >> 4) * 4;
    #pragma unroll
    for (int j = 0; j < 4; ++j) {
        C[(size_t)(rbase + j) * DIM + cn] = f2bf(acc[j] + bn);
    }
}

// ---------------- grouped head GEMM (MFMA, single bf16 W, pipelined) ---------
__global__ __launch_bounds__(256) void head_mfma(
    const unsigned short* __restrict__ H,   // BATCH x DIM bf16
    const float* __restrict__ Wh,           // NHEADS x OUTD x DIM f32
    const float* __restrict__ bh,           // NHEADS x OUTD f32
    const int* __restrict__ bidx,
    const int* __restrict__ gstart,
    const int* __restrict__ gcount,
    float* __restrict__ out)                // BATCH x OUTD f32
{
    const int head = blockIdx.z;
    const int cnt = gcount[head];
    const int m0 = blockIdx.y * 64;
    if (m0 >= cnt) return;
    const int n0 = blockIdx.x * 64;

    __shared__ __align__(16) unsigned short As[2][64][LDK];
    __shared__ __align__(16) unsigned short Ws[2][64][LDK];
    __shared__ int s_b[64];

    const int tid = threadIdx.x;
    if (tid < 64) {
        int mi = m0 + tid;
        s_b[tid] = (mi < cnt) ? bidx[gstart[head] + mi] : -1;
    }
    __syncthreads();

    const int lane = tid & 63;
    const int wid = tid >> 6;
    const int wm = (wid >> 1) * 32;
    const int wn = (wid & 1) * 32;

    f32x4 acc[2][2] = {};

    const int ar = tid >> 3;          // 0..31
    const int ac = (tid & 7) * 8;
    int b0 = s_b[ar];       if (b0 < 0) b0 = 0;
    int b1 = s_b[ar + 32];  if (b1 < 0) b1 = 0;
    const unsigned short* Ap0 = H + (size_t)b0 * DIM + ac;
    const unsigned short* Ap1 = H + (size_t)b1 * DIM + ac;

    const int wr = tid >> 4;          // 0..15
    const int wc = (tid & 15) * 4;
    const float* WhL = Wh + (size_t)head * OUTD * DIM;
    const float* Wp[4];
    #pragma unroll
    for (int p = 0; p < 4; ++p) {
        int r = n0 + wr + p * 16;
        if (r > OUTD - 1) r = OUTD - 1;
        Wp[p] = WhL + (size_t)r * DIM + wc;
    }

    uint4 ra0 = *(const uint4*)(Ap0);
    uint4 ra1 = *(const uint4*)(Ap1);
    float4 rw[4];
    #pragma unroll
    for (int p = 0; p < 4; ++p) rw[p] = *(const float4*)(Wp[p]);

    for (int t = 0; t < DIM / 64; ++t) {
        const int cur = t & 1;
        *(uint4*)&As[cur][ar][ac]      = ra0;
        *(uint4*)&As[cur][ar + 32][ac] = ra1;
        #pragma unroll
        for (int p = 0; p < 4; ++p) {
            ushort4 hi;
            hi.x = f2bf(rw[p].x);
            hi.y = f2bf(rw[p].y);
            hi.z = f2bf(rw[p].z);
            hi.w = f2bf(rw[p].w);
            *(ushort4*)&Ws[cur][wr + p * 16][wc] = hi;
        }
        __syncthreads();
        if (t < DIM / 64 - 1) {
            const int k0 = (t + 1) * 64;
            ra0 = *(const uint4*)(Ap0 + k0);
            ra1 = *(const uint4*)(Ap1 + k0);
            #pragma unroll
            for (int p = 0; p < 4; ++p) rw[p] = *(const float4*)(Wp[p] + k0);
        }
        #pragma unroll
        for (int kk = 0; kk < 2; ++kk) {
            const int ko = kk * 32 + (lane >> 4) * 8;
            bf16x8 a0 = *(const bf16x8*)&As[cur][wm + (lane & 15)][ko];
            bf16x8 a1 = *(const bf16x8*)&As[cur][wm + 16 + (lane & 15)][ko];
            bf16x8 w0 = *(const bf16x8*)&Ws[cur][wn + (lane & 15)][ko];
            bf16x8 w1 = *(const bf16x8*)&Ws[cur][wn + 16 + (lane & 15)][ko];
            acc[0][0] = __builtin_amdgcn_mfma_f32_16x16x32_bf16(a0, w0, acc[0][0], 0, 0, 0);
            acc[0][1] = __builtin_amdgcn_mfma_f32_16x16x32_bf16(a0, w1, acc[0][1], 0, 0, 0);
            acc[1][0] = __builtin_amdgcn_mfma_f32_16x16x32_bf16(a1, w0, acc[1][0], 0, 0, 0);
            acc[1][1] = __builtin_amdgcn_mfma_f32_16x16x32_bf16(a1, w1, acc[1][1], 0, 0, 0);
        }
    }

    const float* bhL = bh + (size_t)head * OUTD;
    #pragma unroll
    for (int fm = 0; fm < 2; ++fm) {
        #pragma unroll
        for (int fn = 0; fn < 2; ++fn) {
            int n = n0 + wn + fn * 16 + (lane & 15);
            if (n >= OUTD) continue;
            float bn = bhL[n];
            #pragma unroll
            for (int j = 0; j < 4; ++j) {
                int mi = wm + fm * 16 + (lane >> 4) * 4 + j;
                int b = s_b[mi];
                if (b >= 0) out[(size_t)b * OUTD + n] = acc[fm][fn][j] + bn;
            }
        }
    }
}

extern "C" void kernel_launch(void* const* d_in, const int* in_sizes, int n_in,
                              void* d_out, int out_size, void* d_ws, size_t ws_size,
                              hipStream_t stream) {
    const float* latent   = (const float*)d_in[0];
    const float* W_mlp    = (const float*)d_in[1];
    const float* b_mlp    = (const float*)d_in[2];
    const float* W_heads  = (const float*)d_in[3];
    const float* b_heads  = (const float*)d_in[4];
    const int*   rule_len = (const int*)d_in[5];
    float* out = (float*)d_out;

    unsigned short* h0 = (unsigned short*)d_ws;
    unsigned short* h1 = h0 + (size_t)BATCH * DIM;
    int* bidx   = (int*)(h1 + (size_t)BATCH * DIM);
    int* gstart = bidx + BATCH;
    int* gcount = gstart + 16;

    group_kernel<<<1, BATCH, 0, stream>>>(rule_len, bidx, gstart, gcount);
    convert_latent<<<(BATCH * DIM / 4) / 256, 256, 0, stream>>>(latent, h0);

    dim3 mgrid(DIM / 32, BATCH / 32);
    const unsigned short* src = h0;
    unsigned short* dst = h1;
    for (int l = 0; l < NLAYERS; ++l) {
        mlp_mfma<<<mgrid, 256, 0, stream>>>(src,
                                            W_mlp + (size_t)l * DIM * DIM,
                                            b_mlp + (size_t)l * DIM,
                                            dst);
        const unsigned short* t = src;
        src = dst;
        dst = (unsigned short*)t;
    }

    dim3 hgrid((OUTD + 63) / 64, BATCH / 64, NHEADS);
    head_mfma<<<hgrid, 256, 0, stream>>>(src, W_heads, b_heads,
                                         bidx, gstart, gcount, out);
}